// Round 6
// baseline (2217.518 us; speedup 1.0000x reference)
//
#include <hip/hip_runtime.h>
#include <math.h>

#define BB 8
#define NN 8192
#define SS 2048
#define KK 32
#define NP (BB*SS*KK)   /* 524288 points through the MLP */
#define EPSF 1e-5f
#define TT 512          /* fps threads: W=2 waves/SIMD (R4 best) */

typedef float v2f __attribute__((ext_vector_type(2)));

// ---------------------------------------------------------------------------
// DPP-based wave64 max of an f64 key (dist_bits<<32 | ~p). Keys are positive
// non-NaN doubles (dist >= 0), so f64 ordering == u64 ordering, and
// v_max_f64 (1 inst) replaces cmp_u64 + 2 cndmask.
// ---------------------------------------------------------------------------
template <int CTRL>
__device__ __forceinline__ double dpp_max_d(double key) {
    int lo = __double2loint(key), hi = __double2hiint(key);
    int nlo = __builtin_amdgcn_update_dpp(lo, lo, CTRL, 0xf, 0xf, false);
    int nhi = __builtin_amdgcn_update_dpp(hi, hi, CTRL, 0xf, 0xf, false);
    return fmax(__hiloint2double(nhi, nlo), key);
}

__device__ __forceinline__ double wave_max_key(double key) {
    key = dpp_max_d<0x111>(key);  // row_shr:1
    key = dpp_max_d<0x112>(key);  // row_shr:2
    key = dpp_max_d<0x114>(key);  // row_shr:4
    key = dpp_max_d<0x118>(key);  // row_shr:8
    key = dpp_max_d<0x142>(key);  // row_bcast:15
    key = dpp_max_d<0x143>(key);  // row_bcast:31
    return key;                   // valid in lane 63
}

// ---------------------------------------------------------------------------
// FPS: one block per batch (cross-WG exchange ~2.5us/iter -> 1 CU/batch is
// structural). R6 = R4 structure (in-loop f64 slot keys -- the only fps win;
// R5's f32 cmp/cndmask argmax regressed +6%, reverted) + 3-slot LDS
// atomic-max tail: lane-63 atomicMax(u64) into skey3[it%3] pre-barrier;
// post-barrier ONE ds_read_b64 -> gi -> lxyz (replaces 2x ds_read_b128 +
// 7-deep max_f64 tree). Slot rotation: slot s zeroed one barrier before its
// atomics; zeroed two barriers after its last reads; max wave skew = one
// phase => race-free. u64 order == f64 order for positive keys.
// Bit-exact: contract(off), ((dx*dx+dy*dy)+dz*dz), exact coord copies.
// ---------------------------------------------------------------------------
__global__ __launch_bounds__(TT) void fps_kernel(const float* __restrict__ xyz,
                                                 float* __restrict__ out_newxyz) {
#pragma clang fp contract(off)
    const int PPT = NN / TT;         // 16 points per thread
    const int NPAIR = PPT / 2;       // 8 packed pairs
    int b = blockIdx.x;
    int t = threadIdx.x;
    int lane = t & 63;
    const float* x = xyz + b * NN * 3;
    float* nout = out_newxyz + b * SS * 3;

    __shared__ float4 lxyz[NN];                        // 128 KB coord copy
    __shared__ __align__(16) unsigned long long skey3[3]; // rotating winner slots

    v2f px2[NPAIR], py2[NPAIR], pz2[NPAIR], d2[NPAIR];
    int lo_c[PPT];                                 // per-slot tie-break ~p (loop-invariant)
#pragma unroll
    for (int s = 0; s < PPT; s++) lo_c[s] = (int)~(unsigned)(t + s * TT);
#pragma unroll
    for (int j = 0; j < NPAIR; j++) {
        int p0 = t + (2 * j) * TT;                    // slot 2j
        int p1 = p0 + TT;                             // slot 2j+1
        float ax = x[p0 * 3 + 0], ay = x[p0 * 3 + 1], az = x[p0 * 3 + 2];
        float bx = x[p1 * 3 + 0], by = x[p1 * 3 + 1], bz = x[p1 * 3 + 2];
        px2[j].x = ax; px2[j].y = bx;
        py2[j].x = ay; py2[j].y = by;
        pz2[j].x = az; pz2[j].y = bz;
        lxyz[p0] = make_float4(ax, ay, az, 0.f);
        lxyz[p1] = make_float4(bx, by, bz, 0.f);
        d2[j].x = 1e10f; d2[j].y = 1e10f;
    }
    if (t == 0) { skey3[0] = 0ull; skey3[1] = 0ull; skey3[2] = 0ull; }
    __syncthreads();
    float4 c0 = lxyz[0];                              // far = 0 initially
    float cx = c0.x, cy = c0.y, cz = c0.z;

    int sl = 0;                                       // it % 3
#pragma unroll 2
    for (int it = 0; it < SS; it++) {
        // store from copies so the store's data regs never alias the tail's
        // ds_read destinations (no hidden vmcnt drain on wave 0)
        float sx = cx, sy = cy, sz = cz;
        if (t == 0) {                                  // record current far point
            nout[it * 3 + 0] = sx;
            nout[it * 3 + 1] = sy;
            nout[it * 3 + 2] = sz;
            skey3[sl == 2 ? 0 : sl + 1] = 0ull;        // zero NEXT slot (safe: see header)
        }
        v2f cxx, cyy, czz;
        cxx.x = cx; cxx.y = cx;
        cyy.x = cy; cyy.y = cy;
        czz.x = cz; czz.y = cz;
        // min-update + in-loop f64 slot keys; 4 independent max_f64 chains
        double acc[4] = {0.0, 0.0, 0.0, 0.0};
#pragma unroll
        for (int j = 0; j < NPAIR; j++) {
            v2f dx = px2[j] - cxx;
            v2f dy = py2[j] - cyy;
            v2f dz = pz2[j] - czz;
            v2f ss = (dx * dx + dy * dy) + dz * dz;
            v2f e  = __builtin_elementwise_min(d2[j], ss);
            d2[j] = e;
            double k0 = __hiloint2double(__float_as_int(e.x), lo_c[2 * j]);
            double k1 = __hiloint2double(__float_as_int(e.y), lo_c[2 * j + 1]);
            double kp = fmax(k0, k1);                  // independent pair-max
            acc[j & 3] = fmax(acc[j & 3], kp);         // static index (unrolled)
        }
        double key = fmax(fmax(acc[0], acc[1]), fmax(acc[2], acc[3]));
        key = wave_max_key(key);                       // DPP, valid in lane 63
        if (lane == 63)
            atomicMax(&skey3[sl], (unsigned long long)__double_as_longlong(key));
        __syncthreads();
        unsigned long long k = skey3[sl];              // one broadcast ds_read_b64
        int gi = (int)(~(unsigned)k) & (NN - 1);
        float4 c = lxyz[gi];                           // one broadcast ds_read_b128
        cx = c.x; cy = c.y; cz = c.z;
        sl = (sl == 2) ? 0 : sl + 1;
    }
}

// ---------------------------------------------------------------------------
// MLP helpers (thread-per-point recompute chain; weights via uniform s_loads)
// ---------------------------------------------------------------------------
__device__ __forceinline__ void load_in6(const float* __restrict__ xyz,
                                         const float* __restrict__ points,
                                         const float* __restrict__ new_xyz,
                                         const int* __restrict__ idx, int p, float inx[6]) {
    int bs = p >> 5;
    int b  = bs >> 11;
    int pt = idx[p];
    const float* xb = xyz + ((long)b * NN + pt) * 3;
    const float* pb = points + ((long)b * NN + pt) * 3;
    const float* nx = new_xyz + bs * 3;
    inx[0] = xb[0] - nx[0];
    inx[1] = xb[1] - nx[1];
    inx[2] = xb[2] - nx[2];
    inx[3] = pb[0];
    inx[4] = pb[1];
    inx[5] = pb[2];
}

template <int CIN, int COUT>
__device__ __forceinline__ void linear(const float* __restrict__ w,
                                       const float* __restrict__ bias,
                                       const float* xin, float* yout) {
#pragma unroll
    for (int o = 0; o < COUT; o++) {
        float acc = bias[o];
#pragma unroll
        for (int j = 0; j < CIN; j++) acc = fmaf(w[o * CIN + j], xin[j], acc);
        yout[o] = acc;
    }
}

// compute per-channel BN scale/shift from raw sums (threads 0..C-1)
template <int C>
__device__ __forceinline__ void bn_coef(const float* __restrict__ stats,
                                        const float* __restrict__ g,
                                        const float* __restrict__ be,
                                        float* s_sc, float* s_sh) {
    int t = threadIdx.x;
    if (t < C) {
        float mean = stats[t] * (1.0f / (float)NP);
        float var  = stats[C + t] * (1.0f / (float)NP) - mean * mean;
        float rstd = 1.0f / sqrtf(var + EPSF);
        float sc = g[t] * rstd;
        s_sc[t] = sc;
        s_sh[t] = be[t] - mean * sc;
    }
    __syncthreads();
}

// block-level channel sums via LDS transpose (33.8KB), one atomic/chan/block
template <int C>
__device__ __forceinline__ void accum_stats(const float* y, float* __restrict__ gstats) {
    __shared__ float buf[256][33];
    int t = threadIdx.x;
#pragma unroll
    for (int h = 0; h < C / 32; h++) {
        __syncthreads();
#pragma unroll
        for (int c = 0; c < 32; c++) buf[t][c] = y[h * 32 + c];
        __syncthreads();
        if (t < 32) {
            float s = 0.f, sq = 0.f;
            for (int r = 0; r < 256; r++) {
                float v = buf[r][t];
                s += v;
                sq = fmaf(v, v, sq);
            }
            atomicAdd(&gstats[h * 32 + t], s);
            atomicAdd(&gstats[C + h * 32 + t], sq);
        }
    }
}

// ---------------------------------------------------------------------------
// Ball query: one wave per query. Ordered compaction of first 32 in-radius
// indices (== reference's where->sort->truncate), pad with first index.
// R6: fused l0 stats tail -- this block's 4 queries own exactly points
// [blockIdx*128, +128); after syncthreads (vmcnt-drained => idx L2-visible
// to this CU), threads <128 compute y0 for one point each (>=128 contribute
// zeros; sums unchanged, NP divisor fixed) and run accum_stats<32>.
// Deletes the separate l0_stats kernel (launch + full gather pass).
// ---------------------------------------------------------------------------
__global__ __launch_bounds__(256) void ballq_kernel(const float* __restrict__ xyz,
                                                    const float* __restrict__ new_xyz,
                                                    int* __restrict__ idx_out,
                                                    const float* __restrict__ points,
                                                    const float* __restrict__ w0,
                                                    const float* __restrict__ b0_,
                                                    float* __restrict__ stats0) {
    int q    = blockIdx.x * 4 + (threadIdx.x >> 6);
    int lane = threadIdx.x & 63;
    int b    = q >> 11;                        // q / SS
    const float* x = xyz + b * NN * 3;
    const float* c = new_xyz + q * 3;
    float cx = c[0], cy = c[1], cz = c[2];
    int* out = idx_out + q * KK;
    const float R2 = (float)(0.2 * 0.2);       // match reference double->f32 cast

    int count = 0;
    int first = -1;
    for (int base = 0; base < NN; base += 64) {
        int p = base + lane;
        float dx = __fsub_rn(x[p * 3 + 0], cx);
        float dy = __fsub_rn(x[p * 3 + 1], cy);
        float dz = __fsub_rn(x[p * 3 + 2], cz);
        float d  = __fadd_rn(__fadd_rn(__fmul_rn(dx, dx), __fmul_rn(dy, dy)),
                             __fmul_rn(dz, dz));
        bool in = !(d > R2);
        unsigned long long m = __ballot(in);
        if (first < 0 && m != 0ull) first = base + __ffsll((unsigned long long)m) - 1;
        int pre = __popcll(m & ((1ull << lane) - 1ull));
        int pos = count + pre;
        if (in && pos < KK) out[pos] = p;
        count += __popcll(m);
        if (count >= KK) break;                 // wave-uniform
    }
    for (int i2 = count + lane; i2 < KK; i2 += 64) out[i2] = first;

    // ---- fused l0 stats (points blockIdx*128 .. +128) ----
    __syncthreads();                            // drains stores: idx visible via L2
    int t = threadIdx.x;
    float y0s[32];
    if (t < 128) {
        int p = blockIdx.x * 128 + t;
        float inx[6];
        load_in6(xyz, points, new_xyz, idx_out, p, inx);
        linear<6, 32>(w0, b0_, inx, y0s);
    } else {
#pragma unroll
        for (int cc = 0; cc < 32; cc++) y0s[cc] = 0.f;
    }
    accum_stats<32>(y0s, stats0);
}

__global__ __launch_bounds__(256) void l1_stats_kernel(
    const float* __restrict__ xyz, const float* __restrict__ points,
    const float* __restrict__ new_xyz, const int* __restrict__ idx,
    const float* __restrict__ w0, const float* __restrict__ b0_,
    const float* __restrict__ g0, const float* __restrict__ be0,
    const float* __restrict__ w1, const float* __restrict__ b1_,
    const float* __restrict__ stats0, float* __restrict__ stats1) {
    __shared__ float sc0[32], sh0[32];
    bn_coef<32>(stats0, g0, be0, sc0, sh0);
    int p = blockIdx.x * 256 + threadIdx.x;
    float inx[6];
    load_in6(xyz, points, new_xyz, idx, p, inx);
    float y0[32];
    linear<6, 32>(w0, b0_, inx, y0);
#pragma unroll
    for (int c = 0; c < 32; c++) y0[c] = fmaxf(fmaf(y0[c], sc0[c], sh0[c]), 0.f);
    float y1[32];
    linear<32, 32>(w1, b1_, y0, y1);
    accum_stats<32>(y1, stats1);
}

__global__ __launch_bounds__(256) void l2_stats_kernel(
    const float* __restrict__ xyz, const float* __restrict__ points,
    const float* __restrict__ new_xyz, const int* __restrict__ idx,
    const float* __restrict__ w0, const float* __restrict__ b0_,
    const float* __restrict__ g0, const float* __restrict__ be0,
    const float* __restrict__ w1, const float* __restrict__ b1_,
    const float* __restrict__ g1, const float* __restrict__ be1,
    const float* __restrict__ w2, const float* __restrict__ b2_,
    const float* __restrict__ stats0, const float* __restrict__ stats1,
    float* __restrict__ stats2) {
    __shared__ float sc0[32], sh0[32], sc1[32], sh1[32];
    bn_coef<32>(stats0, g0, be0, sc0, sh0);
    bn_coef<32>(stats1, g1, be1, sc1, sh1);
    int p = blockIdx.x * 256 + threadIdx.x;
    float inx[6];
    load_in6(xyz, points, new_xyz, idx, p, inx);
    float y0[32];
    linear<6, 32>(w0, b0_, inx, y0);
#pragma unroll
    for (int c = 0; c < 32; c++) y0[c] = fmaxf(fmaf(y0[c], sc0[c], sh0[c]), 0.f);
    float y1[32];
    linear<32, 32>(w1, b1_, y0, y1);
#pragma unroll
    for (int c = 0; c < 32; c++) y1[c] = fmaxf(fmaf(y1[c], sc1[c], sh1[c]), 0.f);
    float y2[64];
    linear<32, 64>(w2, b2_, y1, y2);
    accum_stats<64>(y2, stats2);
}

__global__ __launch_bounds__(256) void final_kernel(
    const float* __restrict__ xyz, const float* __restrict__ points,
    const float* __restrict__ new_xyz, const int* __restrict__ idx,
    const float* __restrict__ w0, const float* __restrict__ b0_,
    const float* __restrict__ g0, const float* __restrict__ be0,
    const float* __restrict__ w1, const float* __restrict__ b1_,
    const float* __restrict__ g1, const float* __restrict__ be1,
    const float* __restrict__ w2, const float* __restrict__ b2_,
    const float* __restrict__ g2, const float* __restrict__ be2,
    const float* __restrict__ stats0, const float* __restrict__ stats1,
    const float* __restrict__ stats2, float* __restrict__ out_points) {
    __shared__ float sc0[32], sh0[32], sc1[32], sh1[32], sc2[64], sh2[64];
    bn_coef<32>(stats0, g0, be0, sc0, sh0);
    bn_coef<32>(stats1, g1, be1, sc1, sh1);
    bn_coef<64>(stats2, g2, be2, sc2, sh2);
    int p = blockIdx.x * 256 + threadIdx.x;
    float inx[6];
    load_in6(xyz, points, new_xyz, idx, p, inx);
    float y0[32];
    linear<6, 32>(w0, b0_, inx, y0);
#pragma unroll
    for (int c = 0; c < 32; c++) y0[c] = fmaxf(fmaf(y0[c], sc0[c], sh0[c]), 0.f);
    float y1[32];
    linear<32, 32>(w1, b1_, y0, y1);
#pragma unroll
    for (int c = 0; c < 32; c++) y1[c] = fmaxf(fmaf(y1[c], sc1[c], sh1[c]), 0.f);
    float y2[64];
    linear<32, 64>(w2, b2_, y1, y2);
    // BN + relu + max over k (k == lane&31; butterfly within each 32-lane half)
#pragma unroll
    for (int c = 0; c < 64; c++) {
        float v = fmaxf(fmaf(y2[c], sc2[c], sh2[c]), 0.f);
#pragma unroll
        for (int off = 1; off < 32; off <<= 1)
            v = fmaxf(v, __shfl_xor(v, off));
        y2[c] = v;
    }
    int lane = threadIdx.x & 63;
    if ((lane & 31) == 0) {                     // k == 0 lanes write their (b,s) row
        int bs = p >> 5;
        float4* o = (float4*)(out_points + (long)bs * 64);
#pragma unroll
        for (int c4 = 0; c4 < 16; c4++)
            o[c4] = make_float4(y2[c4 * 4], y2[c4 * 4 + 1], y2[c4 * 4 + 2], y2[c4 * 4 + 3]);
    }
}

// ---------------------------------------------------------------------------
extern "C" void kernel_launch(void* const* d_in, const int* in_sizes, int n_in,
                              void* d_out, int out_size, void* d_ws, size_t ws_size,
                              hipStream_t stream) {
    (void)in_sizes; (void)n_in; (void)out_size; (void)ws_size;
    const float* xyz    = (const float*)d_in[0];
    const float* points = (const float*)d_in[1];
    const float* w0  = (const float*)d_in[2];
    const float* b0_ = (const float*)d_in[3];
    const float* g0  = (const float*)d_in[4];
    const float* be0 = (const float*)d_in[5];
    const float* w1  = (const float*)d_in[6];
    const float* b1_ = (const float*)d_in[7];
    const float* g1  = (const float*)d_in[8];
    const float* be1 = (const float*)d_in[9];
    const float* w2  = (const float*)d_in[10];
    const float* b2_ = (const float*)d_in[11];
    const float* g2  = (const float*)d_in[12];
    const float* be2 = (const float*)d_in[13];

    float* out        = (float*)d_out;
    float* out_newxyz = out;                 // (8,2048,3)
    float* out_points = out + BB * SS * 3;   // (8,2048,64)

    int*   idx    = (int*)d_ws;              // NP ints = 2MB
    float* stats  = (float*)d_ws + NP;
    float* stats0 = stats;                   // 64 floats (sum32+sq32)
    float* stats1 = stats + 64;              // 64 floats
    float* stats2 = stats + 128;             // 128 floats (sum64+sq64)

    hipMemsetAsync(stats, 0, 256 * sizeof(float), stream);

    fps_kernel<<<BB, TT, 0, stream>>>(xyz, out_newxyz);
    ballq_kernel<<<BB * SS / 4, 256, 0, stream>>>(xyz, out_newxyz, idx,
                                                  points, w0, b0_, stats0);
    l1_stats_kernel<<<NP / 256, 256, 0, stream>>>(xyz, points, out_newxyz, idx,
                                                  w0, b0_, g0, be0, w1, b1_, stats0, stats1);
    l2_stats_kernel<<<NP / 256, 256, 0, stream>>>(xyz, points, out_newxyz, idx,
                                                  w0, b0_, g0, be0, w1, b1_, g1, be1,
                                                  w2, b2_, stats0, stats1, stats2);
    final_kernel<<<NP / 256, 256, 0, stream>>>(xyz, points, out_newxyz, idx,
                                               w0, b0_, g0, be0, w1, b1_, g1, be1,
                                               w2, b2_, g2, be2, stats0, stats1, stats2,
                                               out_points);
}

// Round 7
// 2044.899 us; speedup vs baseline: 1.0844x; 1.0844x over previous
//
#include <hip/hip_runtime.h>
#include <math.h>

#define BB 8
#define NN 8192
#define SS 2048
#define KK 32
#define NP (BB*SS*KK)   /* 524288 points through the MLP */
#define EPSF 1e-5f
#define TT 512          /* fps threads: W=2 waves/SIMD (R4 best config) */

typedef float v2f __attribute__((ext_vector_type(2)));

// ---------------------------------------------------------------------------
// DPP-based wave64 max of an f64 key (dist_bits<<32 | ~p). Keys are positive
// non-NaN doubles (dist >= 0), so f64 ordering == u64 ordering, and
// v_max_f64 (1 inst) replaces cmp_u64 + 2 cndmask.
// ---------------------------------------------------------------------------
template <int CTRL>
__device__ __forceinline__ double dpp_max_d(double key) {
    int lo = __double2loint(key), hi = __double2hiint(key);
    int nlo = __builtin_amdgcn_update_dpp(lo, lo, CTRL, 0xf, 0xf, false);
    int nhi = __builtin_amdgcn_update_dpp(hi, hi, CTRL, 0xf, 0xf, false);
    return fmax(__hiloint2double(nhi, nlo), key);
}

__device__ __forceinline__ double wave_max_key(double key) {
    key = dpp_max_d<0x111>(key);  // row_shr:1
    key = dpp_max_d<0x112>(key);  // row_shr:2
    key = dpp_max_d<0x114>(key);  // row_shr:4
    key = dpp_max_d<0x118>(key);  // row_shr:8
    key = dpp_max_d<0x142>(key);  // row_bcast:15
    key = dpp_max_d<0x143>(key);  // row_bcast:31
    return key;                   // valid in lane 63
}

// ---------------------------------------------------------------------------
// FPS: one block per batch (cross-WG exchange ~2.5us/iter -> 1 CU/batch is
// structural). R7 = R4 structure EXACTLY (in-loop f64 slot keys; parity
// skey[2][NW] LDS exchange; 4x ds_read_b128 + depth-3 max_f64 tree tail --
// R6's LDS atomicMax tail serialized 8 wave-atomics and regressed +118us,
// reverted) + deferred output stores: wave 0's per-iter 3 global stores sat
// on the barrier critical path; now phase ph / thread t captures iteration
// ph*512+t's centroid in registers (static phase index -> no scratch) and
// all stores happen coalesced after the loop. Captured value == what wave 0
// stored at that iteration (centroid selected at end of previous iter).
// Bit-exact: contract(off), ((dx*dx+dy*dy)+dz*dz), exact coord copies,
// f64 key order == u64 key order for positive finite keys; max of
// (dist, ~p) == max dist with smallest-global-index tie-break == np.argmax.
// ---------------------------------------------------------------------------
__global__ __launch_bounds__(TT) void fps_kernel(const float* __restrict__ xyz,
                                                 float* __restrict__ out_newxyz) {
#pragma clang fp contract(off)
    const int PPT = NN / TT;         // 16 points per thread
    const int NPAIR = PPT / 2;       // 8 packed pairs
    const int NW = TT / 64;          // 8 waves
    int b = blockIdx.x;
    int t = threadIdx.x;
    int wid  = t >> 6;               // 0..7
    int lane = t & 63;
    const float* x = xyz + b * NN * 3;
    float* nout = out_newxyz + b * SS * 3;

    __shared__ float4 lxyz[NN];                    // 128 KB coord copy
    __shared__ __align__(16) double skey[2][NW];   // parity wave keys (f64)

    v2f px2[NPAIR], py2[NPAIR], pz2[NPAIR], d2[NPAIR];
    int lo_c[PPT];                                 // per-slot tie-break ~p (loop-invariant)
#pragma unroll
    for (int s = 0; s < PPT; s++) lo_c[s] = (int)~(unsigned)(t + s * TT);
#pragma unroll
    for (int j = 0; j < NPAIR; j++) {
        int p0 = t + (2 * j) * TT;                    // slot 2j
        int p1 = p0 + TT;                             // slot 2j+1
        float ax = x[p0 * 3 + 0], ay = x[p0 * 3 + 1], az = x[p0 * 3 + 2];
        float bx = x[p1 * 3 + 0], by = x[p1 * 3 + 1], bz = x[p1 * 3 + 2];
        px2[j].x = ax; px2[j].y = bx;
        py2[j].x = ay; py2[j].y = by;
        pz2[j].x = az; pz2[j].y = bz;
        lxyz[p0] = make_float4(ax, ay, az, 0.f);
        lxyz[p1] = make_float4(bx, by, bz, 0.f);
        d2[j].x = 1e10f; d2[j].y = 1e10f;
    }
    __syncthreads();
    float4 c0 = lxyz[0];                              // far = 0 initially
    float cx = c0.x, cy = c0.y, cz = c0.z;

    float capx[4], capy[4], capz[4];                  // deferred outputs (static idx)
#pragma unroll
    for (int ph = 0; ph < 4; ph++) {
#pragma unroll 2
        for (int i = 0; i < SS / 4; i++) {            // SS/4 == TT == 512
            int it = ph * (SS / 4) + i;
            if (i == t) {                              // capture this iter's centroid
                capx[ph] = cx; capy[ph] = cy; capz[ph] = cz;
            }
            v2f cxx, cyy, czz;
            cxx.x = cx; cxx.y = cx;
            cyy.x = cy; cyy.y = cy;
            czz.x = cz; czz.y = cz;
            // min-update + in-loop f64 slot keys; 4 independent max_f64 chains
            double acc[4] = {0.0, 0.0, 0.0, 0.0};
#pragma unroll
            for (int j = 0; j < NPAIR; j++) {
                v2f dx = px2[j] - cxx;
                v2f dy = py2[j] - cyy;
                v2f dz = pz2[j] - czz;
                v2f ss = (dx * dx + dy * dy) + dz * dz;
                v2f e  = __builtin_elementwise_min(d2[j], ss);
                d2[j] = e;
                double k0 = __hiloint2double(__float_as_int(e.x), lo_c[2 * j]);
                double k1 = __hiloint2double(__float_as_int(e.y), lo_c[2 * j + 1]);
                double kp = fmax(k0, k1);              // independent pair-max
                acc[j & 3] = fmax(acc[j & 3], kp);     // static index (unrolled)
            }
            double key = fmax(fmax(acc[0], acc[1]), fmax(acc[2], acc[3]));
            key = wave_max_key(key);                   // DPP, valid in lane 63
            if (lane == 63) skey[it & 1][wid] = key;
            __syncthreads();
            const double2* sk = (const double2*)&skey[it & 1][0];
            double2 k01 = sk[0];                       // 4x ds_read_b128
            double2 k23 = sk[1];
            double2 k45 = sk[2];
            double2 k67 = sk[3];
            double ka = fmax(fmax(k01.x, k01.y), fmax(k23.x, k23.y));
            double kb = fmax(fmax(k45.x, k45.y), fmax(k67.x, k67.y));
            double k  = fmax(ka, kb);                  // depth-3 tree
            int gi = (int)(~(unsigned)__double2loint(k)) & (NN - 1);
            float4 c = lxyz[gi];                       // one broadcast ds_read_b128
            cx = c.x; cy = c.y; cz = c.z;
        }
    }
    // coalesced deferred output: thread t wrote iterations ph*512+t
#pragma unroll
    for (int ph = 0; ph < 4; ph++) {
        int it = ph * (SS / 4) + t;
        nout[it * 3 + 0] = capx[ph];
        nout[it * 3 + 1] = capy[ph];
        nout[it * 3 + 2] = capz[ph];
    }
}

// ---------------------------------------------------------------------------
// Ball query: one wave per query. Ordered compaction of first 32 in-radius
// indices (== reference's where->sort->truncate), pad with first index.
// ---------------------------------------------------------------------------
__global__ __launch_bounds__(256) void ballq_kernel(const float* __restrict__ xyz,
                                                    const float* __restrict__ new_xyz,
                                                    int* __restrict__ idx_out) {
    int q    = blockIdx.x * 4 + (threadIdx.x >> 6);
    int lane = threadIdx.x & 63;
    int b    = q >> 11;                        // q / SS
    const float* x = xyz + b * NN * 3;
    const float* c = new_xyz + q * 3;
    float cx = c[0], cy = c[1], cz = c[2];
    int* out = idx_out + q * KK;
    const float R2 = (float)(0.2 * 0.2);       // match reference double->f32 cast

    int count = 0;
    int first = -1;
    for (int base = 0; base < NN; base += 64) {
        int p = base + lane;
        float dx = __fsub_rn(x[p * 3 + 0], cx);
        float dy = __fsub_rn(x[p * 3 + 1], cy);
        float dz = __fsub_rn(x[p * 3 + 2], cz);
        float d  = __fadd_rn(__fadd_rn(__fmul_rn(dx, dx), __fmul_rn(dy, dy)),
                             __fmul_rn(dz, dz));
        bool in = !(d > R2);
        unsigned long long m = __ballot(in);
        if (first < 0 && m != 0ull) first = base + __ffsll((unsigned long long)m) - 1;
        int pre = __popcll(m & ((1ull << lane) - 1ull));
        int pos = count + pre;
        if (in && pos < KK) out[pos] = p;
        count += __popcll(m);
        if (count >= KK) break;                 // wave-uniform
    }
    for (int i2 = count + lane; i2 < KK; i2 += 64) out[i2] = first;
}

// ---------------------------------------------------------------------------
// MLP helpers (thread-per-point recompute chain; weights via uniform s_loads)
// ---------------------------------------------------------------------------
__device__ __forceinline__ void load_in6(const float* __restrict__ xyz,
                                         const float* __restrict__ points,
                                         const float* __restrict__ new_xyz,
                                         const int* __restrict__ idx, int p, float inx[6]) {
    int bs = p >> 5;
    int b  = bs >> 11;
    int pt = idx[p];
    const float* xb = xyz + ((long)b * NN + pt) * 3;
    const float* pb = points + ((long)b * NN + pt) * 3;
    const float* nx = new_xyz + bs * 3;
    inx[0] = xb[0] - nx[0];
    inx[1] = xb[1] - nx[1];
    inx[2] = xb[2] - nx[2];
    inx[3] = pb[0];
    inx[4] = pb[1];
    inx[5] = pb[2];
}

template <int CIN, int COUT>
__device__ __forceinline__ void linear(const float* __restrict__ w,
                                       const float* __restrict__ bias,
                                       const float* xin, float* yout) {
#pragma unroll
    for (int o = 0; o < COUT; o++) {
        float acc = bias[o];
#pragma unroll
        for (int j = 0; j < CIN; j++) acc = fmaf(w[o * CIN + j], xin[j], acc);
        yout[o] = acc;
    }
}

// compute per-channel BN scale/shift from raw sums (threads 0..C-1)
template <int C>
__device__ __forceinline__ void bn_coef(const float* __restrict__ stats,
                                        const float* __restrict__ g,
                                        const float* __restrict__ be,
                                        float* s_sc, float* s_sh) {
    int t = threadIdx.x;
    if (t < C) {
        float mean = stats[t] * (1.0f / (float)NP);
        float var  = stats[C + t] * (1.0f / (float)NP) - mean * mean;
        float rstd = 1.0f / sqrtf(var + EPSF);
        float sc = g[t] * rstd;
        s_sc[t] = sc;
        s_sh[t] = be[t] - mean * sc;
    }
    __syncthreads();
}

// block-level channel sums via LDS transpose (33.8KB), one atomic/chan/block
template <int C>
__device__ __forceinline__ void accum_stats(const float* y, float* __restrict__ gstats) {
    __shared__ float buf[256][33];
    int t = threadIdx.x;
#pragma unroll
    for (int h = 0; h < C / 32; h++) {
        __syncthreads();
#pragma unroll
        for (int c = 0; c < 32; c++) buf[t][c] = y[h * 32 + c];
        __syncthreads();
        if (t < 32) {
            float s = 0.f, sq = 0.f;
            for (int r = 0; r < 256; r++) {
                float v = buf[r][t];
                s += v;
                sq = fmaf(v, v, sq);
            }
            atomicAdd(&gstats[h * 32 + t], s);
            atomicAdd(&gstats[C + h * 32 + t], sq);
        }
    }
}

__global__ __launch_bounds__(256) void l0_stats_kernel(
    const float* __restrict__ xyz, const float* __restrict__ points,
    const float* __restrict__ new_xyz, const int* __restrict__ idx,
    const float* __restrict__ w0, const float* __restrict__ b0_,
    float* __restrict__ stats0) {
    int p = blockIdx.x * 256 + threadIdx.x;
    float inx[6];
    load_in6(xyz, points, new_xyz, idx, p, inx);
    float y0[32];
    linear<6, 32>(w0, b0_, inx, y0);
    accum_stats<32>(y0, stats0);
}

__global__ __launch_bounds__(256) void l1_stats_kernel(
    const float* __restrict__ xyz, const float* __restrict__ points,
    const float* __restrict__ new_xyz, const int* __restrict__ idx,
    const float* __restrict__ w0, const float* __restrict__ b0_,
    const float* __restrict__ g0, const float* __restrict__ be0,
    const float* __restrict__ w1, const float* __restrict__ b1_,
    const float* __restrict__ stats0, float* __restrict__ stats1) {
    __shared__ float sc0[32], sh0[32];
    bn_coef<32>(stats0, g0, be0, sc0, sh0);
    int p = blockIdx.x * 256 + threadIdx.x;
    float inx[6];
    load_in6(xyz, points, new_xyz, idx, p, inx);
    float y0[32];
    linear<6, 32>(w0, b0_, inx, y0);
#pragma unroll
    for (int c = 0; c < 32; c++) y0[c] = fmaxf(fmaf(y0[c], sc0[c], sh0[c]), 0.f);
    float y1[32];
    linear<32, 32>(w1, b1_, y0, y1);
    accum_stats<32>(y1, stats1);
}

__global__ __launch_bounds__(256) void l2_stats_kernel(
    const float* __restrict__ xyz, const float* __restrict__ points,
    const float* __restrict__ new_xyz, const int* __restrict__ idx,
    const float* __restrict__ w0, const float* __restrict__ b0_,
    const float* __restrict__ g0, const float* __restrict__ be0,
    const float* __restrict__ w1, const float* __restrict__ b1_,
    const float* __restrict__ g1, const float* __restrict__ be1,
    const float* __restrict__ w2, const float* __restrict__ b2_,
    const float* __restrict__ stats0, const float* __restrict__ stats1,
    float* __restrict__ stats2) {
    __shared__ float sc0[32], sh0[32], sc1[32], sh1[32];
    bn_coef<32>(stats0, g0, be0, sc0, sh0);
    bn_coef<32>(stats1, g1, be1, sc1, sh1);
    int p = blockIdx.x * 256 + threadIdx.x;
    float inx[6];
    load_in6(xyz, points, new_xyz, idx, p, inx);
    float y0[32];
    linear<6, 32>(w0, b0_, inx, y0);
#pragma unroll
    for (int c = 0; c < 32; c++) y0[c] = fmaxf(fmaf(y0[c], sc0[c], sh0[c]), 0.f);
    float y1[32];
    linear<32, 32>(w1, b1_, y0, y1);
#pragma unroll
    for (int c = 0; c < 32; c++) y1[c] = fmaxf(fmaf(y1[c], sc1[c], sh1[c]), 0.f);
    float y2[64];
    linear<32, 64>(w2, b2_, y1, y2);
    accum_stats<64>(y2, stats2);
}

__global__ __launch_bounds__(256) void final_kernel(
    const float* __restrict__ xyz, const float* __restrict__ points,
    const float* __restrict__ new_xyz, const int* __restrict__ idx,
    const float* __restrict__ w0, const float* __restrict__ b0_,
    const float* __restrict__ g0, const float* __restrict__ be0,
    const float* __restrict__ w1, const float* __restrict__ b1_,
    const float* __restrict__ g1, const float* __restrict__ be1,
    const float* __restrict__ w2, const float* __restrict__ b2_,
    const float* __restrict__ g2, const float* __restrict__ be2,
    const float* __restrict__ stats0, const float* __restrict__ stats1,
    const float* __restrict__ stats2, float* __restrict__ out_points) {
    __shared__ float sc0[32], sh0[32], sc1[32], sh1[32], sc2[64], sh2[64];
    bn_coef<32>(stats0, g0, be0, sc0, sh0);
    bn_coef<32>(stats1, g1, be1, sc1, sh1);
    bn_coef<64>(stats2, g2, be2, sc2, sh2);
    int p = blockIdx.x * 256 + threadIdx.x;
    float inx[6];
    load_in6(xyz, points, new_xyz, idx, p, inx);
    float y0[32];
    linear<6, 32>(w0, b0_, inx, y0);
#pragma unroll
    for (int c = 0; c < 32; c++) y0[c] = fmaxf(fmaf(y0[c], sc0[c], sh0[c]), 0.f);
    float y1[32];
    linear<32, 32>(w1, b1_, y0, y1);
#pragma unroll
    for (int c = 0; c < 32; c++) y1[c] = fmaxf(fmaf(y1[c], sc1[c], sh1[c]), 0.f);
    float y2[64];
    linear<32, 64>(w2, b2_, y1, y2);
    // BN + relu + max over k (k == lane&31; butterfly within each 32-lane half)
#pragma unroll
    for (int c = 0; c < 64; c++) {
        float v = fmaxf(fmaf(y2[c], sc2[c], sh2[c]), 0.f);
#pragma unroll
        for (int off = 1; off < 32; off <<= 1)
            v = fmaxf(v, __shfl_xor(v, off));
        y2[c] = v;
    }
    int lane = threadIdx.x & 63;
    if ((lane & 31) == 0) {                     // k == 0 lanes write their (b,s) row
        int bs = p >> 5;
        float4* o = (float4*)(out_points + (long)bs * 64);
#pragma unroll
        for (int c4 = 0; c4 < 16; c4++)
            o[c4] = make_float4(y2[c4 * 4], y2[c4 * 4 + 1], y2[c4 * 4 + 2], y2[c4 * 4 + 3]);
    }
}

// ---------------------------------------------------------------------------
extern "C" void kernel_launch(void* const* d_in, const int* in_sizes, int n_in,
                              void* d_out, int out_size, void* d_ws, size_t ws_size,
                              hipStream_t stream) {
    (void)in_sizes; (void)n_in; (void)out_size; (void)ws_size;
    const float* xyz    = (const float*)d_in[0];
    const float* points = (const float*)d_in[1];
    const float* w0  = (const float*)d_in[2];
    const float* b0_ = (const float*)d_in[3];
    const float* g0  = (const float*)d_in[4];
    const float* be0 = (const float*)d_in[5];
    const float* w1  = (const float*)d_in[6];
    const float* b1_ = (const float*)d_in[7];
    const float* g1  = (const float*)d_in[8];
    const float* be1 = (const float*)d_in[9];
    const float* w2  = (const float*)d_in[10];
    const float* b2_ = (const float*)d_in[11];
    const float* g2  = (const float*)d_in[12];
    const float* be2 = (const float*)d_in[13];

    float* out        = (float*)d_out;
    float* out_newxyz = out;                 // (8,2048,3)
    float* out_points = out + BB * SS * 3;   // (8,2048,64)

    int*   idx    = (int*)d_ws;              // NP ints = 2MB
    float* stats  = (float*)d_ws + NP;
    float* stats0 = stats;                   // 64 floats (sum32+sq32)
    float* stats1 = stats + 64;              // 64 floats
    float* stats2 = stats + 128;             // 128 floats (sum64+sq64)

    hipMemsetAsync(stats, 0, 256 * sizeof(float), stream);

    fps_kernel<<<BB, TT, 0, stream>>>(xyz, out_newxyz);
    ballq_kernel<<<BB * SS / 4, 256, 0, stream>>>(xyz, out_newxyz, idx);
    l0_stats_kernel<<<NP / 256, 256, 0, stream>>>(xyz, points, out_newxyz, idx, w0, b0_, stats0);
    l1_stats_kernel<<<NP / 256, 256, 0, stream>>>(xyz, points, out_newxyz, idx,
                                                  w0, b0_, g0, be0, w1, b1_, stats0, stats1);
    l2_stats_kernel<<<NP / 256, 256, 0, stream>>>(xyz, points, out_newxyz, idx,
                                                  w0, b0_, g0, be0, w1, b1_, g1, be1,
                                                  w2, b2_, stats0, stats1, stats2);
    final_kernel<<<NP / 256, 256, 0, stream>>>(xyz, points, out_newxyz, idx,
                                               w0, b0_, g0, be0, w1, b1_, g1, be1,
                                               w2, b2_, g2, be2, stats0, stats1, stats2,
                                               out_points);
}

// Round 8
// 1978.133 us; speedup vs baseline: 1.1210x; 1.0338x over previous
//
#include <hip/hip_runtime.h>
#include <math.h>

#define BB 8
#define NN 8192
#define SS 2048
#define KK 32
#define NP (BB*SS*KK)   /* 524288 points through the MLP */
#define EPSF 1e-5f
#define TT 512          /* fps threads: W=2 waves/SIMD (R4 best config; R5/R6/R7
                           variants all regressed -> R4 inner loop is frozen) */

typedef float v2f __attribute__((ext_vector_type(2)));

// ---------------------------------------------------------------------------
// DPP-based wave64 max of an f64 key (dist_bits<<32 | ~p). Keys are positive
// non-NaN doubles (dist >= 0), so f64 ordering == u64 ordering, and
// v_max_f64 (1 inst) replaces cmp_u64 + 2 cndmask.
// ---------------------------------------------------------------------------
template <int CTRL>
__device__ __forceinline__ double dpp_max_d(double key) {
    int lo = __double2loint(key), hi = __double2hiint(key);
    int nlo = __builtin_amdgcn_update_dpp(lo, lo, CTRL, 0xf, 0xf, false);
    int nhi = __builtin_amdgcn_update_dpp(hi, hi, CTRL, 0xf, 0xf, false);
    return fmax(__hiloint2double(nhi, nlo), key);
}

__device__ __forceinline__ double wave_max_key(double key) {
    key = dpp_max_d<0x111>(key);  // row_shr:1
    key = dpp_max_d<0x112>(key);  // row_shr:2
    key = dpp_max_d<0x114>(key);  // row_shr:4
    key = dpp_max_d<0x118>(key);  // row_shr:8
    key = dpp_max_d<0x142>(key);  // row_bcast:15
    key = dpp_max_d<0x143>(key);  // row_bcast:31
    return key;                   // valid in lane 63
}

// ---------------------------------------------------------------------------
// FPS: one block per batch (cross-WG exchange ~2.5us/iter -> 1 CU/batch is
// structural). R8 = R4 fps VERBATIM (fps floor: R5 f32-resolve +89us,
// R6 atomic tail +118us, R7 deferred stores +17us all regressed).
// In-loop f64 slot keys; parity skey[2][NW] exchange; depth-3 max_f64 tree.
// Bit-exact: contract(off), ((dx*dx+dy*dy)+dz*dz), exact coord copies,
// f64 key order == u64 order for positive finite keys; max of (dist,~p)
// == max dist with smallest-global-index tie-break == np.argmax.
// ---------------------------------------------------------------------------
__global__ __launch_bounds__(TT) void fps_kernel(const float* __restrict__ xyz,
                                                 float* __restrict__ out_newxyz) {
#pragma clang fp contract(off)
    const int PPT = NN / TT;         // 16 points per thread
    const int NPAIR = PPT / 2;       // 8 packed pairs
    const int NW = TT / 64;          // 8 waves
    int b = blockIdx.x;
    int t = threadIdx.x;
    int wid  = t >> 6;               // 0..7
    int lane = t & 63;
    const float* x = xyz + b * NN * 3;
    float* nout = out_newxyz + b * SS * 3;

    __shared__ float4 lxyz[NN];                    // 128 KB coord copy
    __shared__ __align__(16) double skey[2][NW];   // parity wave keys (f64)

    v2f px2[NPAIR], py2[NPAIR], pz2[NPAIR], d2[NPAIR];
    int lo_c[PPT];                                 // per-slot tie-break ~p (loop-invariant)
#pragma unroll
    for (int s = 0; s < PPT; s++) lo_c[s] = (int)~(unsigned)(t + s * TT);
#pragma unroll
    for (int j = 0; j < NPAIR; j++) {
        int p0 = t + (2 * j) * TT;                    // slot 2j
        int p1 = p0 + TT;                             // slot 2j+1
        float ax = x[p0 * 3 + 0], ay = x[p0 * 3 + 1], az = x[p0 * 3 + 2];
        float bx = x[p1 * 3 + 0], by = x[p1 * 3 + 1], bz = x[p1 * 3 + 2];
        px2[j].x = ax; px2[j].y = bx;
        py2[j].x = ay; py2[j].y = by;
        pz2[j].x = az; pz2[j].y = bz;
        lxyz[p0] = make_float4(ax, ay, az, 0.f);
        lxyz[p1] = make_float4(bx, by, bz, 0.f);
        d2[j].x = 1e10f; d2[j].y = 1e10f;
    }
    __syncthreads();
    float4 c0 = lxyz[0];                              // far = 0 initially
    float cx = c0.x, cy = c0.y, cz = c0.z;

#pragma unroll 2
    for (int it = 0; it < SS; it++) {
        // store from copies so the store's data regs never alias the tail's
        // ds_read destinations (no hidden vmcnt drain on wave 0)
        float sx = cx, sy = cy, sz = cz;
        if (t == 0) {                                  // record current far point
            nout[it * 3 + 0] = sx;
            nout[it * 3 + 1] = sy;
            nout[it * 3 + 2] = sz;
        }
        v2f cxx, cyy, czz;
        cxx.x = cx; cxx.y = cx;
        cyy.x = cy; cyy.y = cy;
        czz.x = cz; czz.y = cz;
        // min-update + in-loop f64 slot keys; 4 independent max_f64 chains
        double acc[4] = {0.0, 0.0, 0.0, 0.0};
#pragma unroll
        for (int j = 0; j < NPAIR; j++) {
            v2f dx = px2[j] - cxx;
            v2f dy = py2[j] - cyy;
            v2f dz = pz2[j] - czz;
            v2f ss = (dx * dx + dy * dy) + dz * dz;
            v2f e  = __builtin_elementwise_min(d2[j], ss);
            d2[j] = e;
            double k0 = __hiloint2double(__float_as_int(e.x), lo_c[2 * j]);
            double k1 = __hiloint2double(__float_as_int(e.y), lo_c[2 * j + 1]);
            double kp = fmax(k0, k1);                  // independent pair-max
            acc[j & 3] = fmax(acc[j & 3], kp);         // static index (unrolled)
        }
        double key = fmax(fmax(acc[0], acc[1]), fmax(acc[2], acc[3]));
        key = wave_max_key(key);                       // DPP, valid in lane 63
        if (lane == 63) skey[it & 1][wid] = key;
        __syncthreads();
        const double2* sk = (const double2*)&skey[it & 1][0];
        double2 k01 = sk[0];                           // 4x ds_read_b128
        double2 k23 = sk[1];
        double2 k45 = sk[2];
        double2 k67 = sk[3];
        double ka = fmax(fmax(k01.x, k01.y), fmax(k23.x, k23.y));
        double kb = fmax(fmax(k45.x, k45.y), fmax(k67.x, k67.y));
        double k  = fmax(ka, kb);                      // depth-3 tree
        int gi = (int)(~(unsigned)__double2loint(k)) & (NN - 1);
        float4 c = lxyz[gi];                           // one broadcast ds_read_b128
        cx = c.x; cy = c.y; cz = c.z;
    }
}

// ---------------------------------------------------------------------------
// Ball query: one wave per query. R8: 2 points per lane per chunk (128 pts).
// FPS centers sit in the sparse shell -> count>=32 early-exit almost never
// fires -> every wave scans all of N; vectorizing halves iterations and
// load count (3x dwordx2, 8B-aligned since (base+2l)*12 % 8 == 0).
// Ordered compaction preserved: pre0 = popc(m0&below)+popc(m1&below),
// pre1 = pre0 + in0 gives exact index order; first = min(2*ffs(m0)-2,
// 2*ffs(m1)-1). Same __f*_rn arithmetic, same R2, same truncate/pad.
// ---------------------------------------------------------------------------
__global__ __launch_bounds__(256) void ballq_kernel(const float* __restrict__ xyz,
                                                    const float* __restrict__ new_xyz,
                                                    int* __restrict__ idx_out) {
    int q    = blockIdx.x * 4 + (threadIdx.x >> 6);
    int lane = threadIdx.x & 63;
    int b    = q >> 11;                        // q / SS
    const float* x = xyz + b * NN * 3;
    const float* c = new_xyz + q * 3;
    float cx = c[0], cy = c[1], cz = c[2];
    int* out = idx_out + q * KK;
    const float R2 = (float)(0.2 * 0.2);       // match reference double->f32 cast

    int count = 0;
    int first = -1;
    unsigned long long below = (1ull << lane) - 1ull;
    for (int base = 0; base < NN; base += 128) {
        int p0 = base + 2 * lane;
        int p1 = p0 + 1;
        const float* xp = x + p0 * 3;
        float2 v01 = *(const float2*)(xp);         // x0 y0
        float2 v23 = *(const float2*)(xp + 2);     // z0 x1
        float2 v45 = *(const float2*)(xp + 4);     // y1 z1
        float dx0 = __fsub_rn(v01.x, cx);
        float dy0 = __fsub_rn(v01.y, cy);
        float dz0 = __fsub_rn(v23.x, cz);
        float dx1 = __fsub_rn(v23.y, cx);
        float dy1 = __fsub_rn(v45.x, cy);
        float dz1 = __fsub_rn(v45.y, cz);
        float d0 = __fadd_rn(__fadd_rn(__fmul_rn(dx0, dx0), __fmul_rn(dy0, dy0)),
                             __fmul_rn(dz0, dz0));
        float d1 = __fadd_rn(__fadd_rn(__fmul_rn(dx1, dx1), __fmul_rn(dy1, dy1)),
                             __fmul_rn(dz1, dz1));
        bool in0 = !(d0 > R2);
        bool in1 = !(d1 > R2);
        unsigned long long m0 = __ballot(in0);
        unsigned long long m1 = __ballot(in1);
        if (first < 0 && (m0 | m1) != 0ull) {
            int c0 = m0 ? (2 * (__ffsll(m0) - 1))     : 9999;
            int c1 = m1 ? (2 * (__ffsll(m1) - 1) + 1) : 9999;
            first = base + (c0 < c1 ? c0 : c1);
        }
        int pre0 = __popcll(m0 & below) + __popcll(m1 & below);
        int pre1 = pre0 + (in0 ? 1 : 0);
        int pos0 = count + pre0;
        int pos1 = count + pre1;
        if (in0 && pos0 < KK) out[pos0] = p0;
        if (in1 && pos1 < KK) out[pos1] = p1;
        count += __popcll(m0) + __popcll(m1);
        if (count >= KK) break;                 // wave-uniform
    }
    for (int i2 = count + lane; i2 < KK; i2 += 64) out[i2] = first;
}

// ---------------------------------------------------------------------------
// MLP helpers (thread-per-point recompute chain; weights via uniform s_loads)
// ---------------------------------------------------------------------------
__device__ __forceinline__ void load_in6(const float* __restrict__ xyz,
                                         const float* __restrict__ points,
                                         const float* __restrict__ new_xyz,
                                         const int* __restrict__ idx, int p, float inx[6]) {
    int bs = p >> 5;
    int b  = bs >> 11;
    int pt = idx[p];
    const float* xb = xyz + ((long)b * NN + pt) * 3;
    const float* pb = points + ((long)b * NN + pt) * 3;
    const float* nx = new_xyz + bs * 3;
    inx[0] = xb[0] - nx[0];
    inx[1] = xb[1] - nx[1];
    inx[2] = xb[2] - nx[2];
    inx[3] = pb[0];
    inx[4] = pb[1];
    inx[5] = pb[2];
}

template <int CIN, int COUT>
__device__ __forceinline__ void linear(const float* __restrict__ w,
                                       const float* __restrict__ bias,
                                       const float* xin, float* yout) {
#pragma unroll
    for (int o = 0; o < COUT; o++) {
        float acc = bias[o];
#pragma unroll
        for (int j = 0; j < CIN; j++) acc = fmaf(w[o * CIN + j], xin[j], acc);
        yout[o] = acc;
    }
}

// compute per-channel BN scale/shift from raw sums (threads 0..C-1)
template <int C>
__device__ __forceinline__ void bn_coef(const float* __restrict__ stats,
                                        const float* __restrict__ g,
                                        const float* __restrict__ be,
                                        float* s_sc, float* s_sh) {
    int t = threadIdx.x;
    if (t < C) {
        float mean = stats[t] * (1.0f / (float)NP);
        float var  = stats[C + t] * (1.0f / (float)NP) - mean * mean;
        float rstd = 1.0f / sqrtf(var + EPSF);
        float sc = g[t] * rstd;
        s_sc[t] = sc;
        s_sh[t] = be[t] - mean * sc;
    }
    __syncthreads();
}

// block-level channel sums via LDS transpose. R8: parallel 2-level reduce --
// all 256 threads sum 32 rows of one channel (bank = (r+ch)%32, 2 lanes/bank
// = free), 8 partials/channel in ps[], threads<32 fold 8 + one atomic.
// Serial depth 256 -> 40; phase 1 fully occupied. (Summation regrouping only;
// R6 showed blockwise regrouping stays within tolerance.)
template <int C>
__device__ __forceinline__ void accum_stats(const float* y, float* __restrict__ gstats) {
    __shared__ float buf[256][33];
    __shared__ float ps[2][8][33];
    int t = threadIdx.x;
    int ch  = t & 31;
    int seg = t >> 5;                 // 0..7 -> rows seg*32..+32
#pragma unroll
    for (int h = 0; h < C / 32; h++) {
        __syncthreads();
#pragma unroll
        for (int c = 0; c < 32; c++) buf[t][c] = y[h * 32 + c];
        __syncthreads();
        float s = 0.f, sq = 0.f;
#pragma unroll
        for (int r = 0; r < 32; r++) {
            float v = buf[seg * 32 + r][ch];
            s += v;
            sq = fmaf(v, v, sq);
        }
        ps[0][seg][ch] = s;
        ps[1][seg][ch] = sq;
        __syncthreads();
        if (t < 32) {
            float S = 0.f, Q = 0.f;
#pragma unroll
            for (int g = 0; g < 8; g++) {
                S += ps[0][g][t];
                Q += ps[1][g][t];
            }
            atomicAdd(&gstats[h * 32 + t], S);
            atomicAdd(&gstats[C + h * 32 + t], Q);
        }
    }
}

__global__ __launch_bounds__(256) void l0_stats_kernel(
    const float* __restrict__ xyz, const float* __restrict__ points,
    const float* __restrict__ new_xyz, const int* __restrict__ idx,
    const float* __restrict__ w0, const float* __restrict__ b0_,
    float* __restrict__ stats0) {
    int p = blockIdx.x * 256 + threadIdx.x;
    float inx[6];
    load_in6(xyz, points, new_xyz, idx, p, inx);
    float y0[32];
    linear<6, 32>(w0, b0_, inx, y0);
    accum_stats<32>(y0, stats0);
}

__global__ __launch_bounds__(256) void l1_stats_kernel(
    const float* __restrict__ xyz, const float* __restrict__ points,
    const float* __restrict__ new_xyz, const int* __restrict__ idx,
    const float* __restrict__ w0, const float* __restrict__ b0_,
    const float* __restrict__ g0, const float* __restrict__ be0,
    const float* __restrict__ w1, const float* __restrict__ b1_,
    const float* __restrict__ stats0, float* __restrict__ stats1) {
    __shared__ float sc0[32], sh0[32];
    bn_coef<32>(stats0, g0, be0, sc0, sh0);
    int p = blockIdx.x * 256 + threadIdx.x;
    float inx[6];
    load_in6(xyz, points, new_xyz, idx, p, inx);
    float y0[32];
    linear<6, 32>(w0, b0_, inx, y0);
#pragma unroll
    for (int c = 0; c < 32; c++) y0[c] = fmaxf(fmaf(y0[c], sc0[c], sh0[c]), 0.f);
    float y1[32];
    linear<32, 32>(w1, b1_, y0, y1);
    accum_stats<32>(y1, stats1);
}

__global__ __launch_bounds__(256) void l2_stats_kernel(
    const float* __restrict__ xyz, const float* __restrict__ points,
    const float* __restrict__ new_xyz, const int* __restrict__ idx,
    const float* __restrict__ w0, const float* __restrict__ b0_,
    const float* __restrict__ g0, const float* __restrict__ be0,
    const float* __restrict__ w1, const float* __restrict__ b1_,
    const float* __restrict__ g1, const float* __restrict__ be1,
    const float* __restrict__ w2, const float* __restrict__ b2_,
    const float* __restrict__ stats0, const float* __restrict__ stats1,
    float* __restrict__ stats2) {
    __shared__ float sc0[32], sh0[32], sc1[32], sh1[32];
    bn_coef<32>(stats0, g0, be0, sc0, sh0);
    bn_coef<32>(stats1, g1, be1, sc1, sh1);
    int p = blockIdx.x * 256 + threadIdx.x;
    float inx[6];
    load_in6(xyz, points, new_xyz, idx, p, inx);
    float y0[32];
    linear<6, 32>(w0, b0_, inx, y0);
#pragma unroll
    for (int c = 0; c < 32; c++) y0[c] = fmaxf(fmaf(y0[c], sc0[c], sh0[c]), 0.f);
    float y1[32];
    linear<32, 32>(w1, b1_, y0, y1);
#pragma unroll
    for (int c = 0; c < 32; c++) y1[c] = fmaxf(fmaf(y1[c], sc1[c], sh1[c]), 0.f);
    float y2[64];
    linear<32, 64>(w2, b2_, y1, y2);
    accum_stats<64>(y2, stats2);
}

__global__ __launch_bounds__(256) void final_kernel(
    const float* __restrict__ xyz, const float* __restrict__ points,
    const float* __restrict__ new_xyz, const int* __restrict__ idx,
    const float* __restrict__ w0, const float* __restrict__ b0_,
    const float* __restrict__ g0, const float* __restrict__ be0,
    const float* __restrict__ w1, const float* __restrict__ b1_,
    const float* __restrict__ g1, const float* __restrict__ be1,
    const float* __restrict__ w2, const float* __restrict__ b2_,
    const float* __restrict__ g2, const float* __restrict__ be2,
    const float* __restrict__ stats0, const float* __restrict__ stats1,
    const float* __restrict__ stats2, float* __restrict__ out_points) {
    __shared__ float sc0[32], sh0[32], sc1[32], sh1[32], sc2[64], sh2[64];
    bn_coef<32>(stats0, g0, be0, sc0, sh0);
    bn_coef<32>(stats1, g1, be1, sc1, sh1);
    bn_coef<64>(stats2, g2, be2, sc2, sh2);
    int p = blockIdx.x * 256 + threadIdx.x;
    float inx[6];
    load_in6(xyz, points, new_xyz, idx, p, inx);
    float y0[32];
    linear<6, 32>(w0, b0_, inx, y0);
#pragma unroll
    for (int c = 0; c < 32; c++) y0[c] = fmaxf(fmaf(y0[c], sc0[c], sh0[c]), 0.f);
    float y1[32];
    linear<32, 32>(w1, b1_, y0, y1);
#pragma unroll
    for (int c = 0; c < 32; c++) y1[c] = fmaxf(fmaf(y1[c], sc1[c], sh1[c]), 0.f);
    float y2[64];
    linear<32, 64>(w2, b2_, y1, y2);
    // BN + relu + max over k (k == lane&31; butterfly within each 32-lane half)
#pragma unroll
    for (int c = 0; c < 64; c++) {
        float v = fmaxf(fmaf(y2[c], sc2[c], sh2[c]), 0.f);
#pragma unroll
        for (int off = 1; off < 32; off <<= 1)
            v = fmaxf(v, __shfl_xor(v, off));
        y2[c] = v;
    }
    int lane = threadIdx.x & 63;
    if ((lane & 31) == 0) {                     // k == 0 lanes write their (b,s) row
        int bs = p >> 5;
        float4* o = (float4*)(out_points + (long)bs * 64);
#pragma unroll
        for (int c4 = 0; c4 < 16; c4++)
            o[c4] = make_float4(y2[c4 * 4], y2[c4 * 4 + 1], y2[c4 * 4 + 2], y2[c4 * 4 + 3]);
    }
}

// ---------------------------------------------------------------------------
extern "C" void kernel_launch(void* const* d_in, const int* in_sizes, int n_in,
                              void* d_out, int out_size, void* d_ws, size_t ws_size,
                              hipStream_t stream) {
    (void)in_sizes; (void)n_in; (void)out_size; (void)ws_size;
    const float* xyz    = (const float*)d_in[0];
    const float* points = (const float*)d_in[1];
    const float* w0  = (const float*)d_in[2];
    const float* b0_ = (const float*)d_in[3];
    const float* g0  = (const float*)d_in[4];
    const float* be0 = (const float*)d_in[5];
    const float* w1  = (const float*)d_in[6];
    const float* b1_ = (const float*)d_in[7];
    const float* g1  = (const float*)d_in[8];
    const float* be1 = (const float*)d_in[9];
    const float* w2  = (const float*)d_in[10];
    const float* b2_ = (const float*)d_in[11];
    const float* g2  = (const float*)d_in[12];
    const float* be2 = (const float*)d_in[13];

    float* out        = (float*)d_out;
    float* out_newxyz = out;                 // (8,2048,3)
    float* out_points = out + BB * SS * 3;   // (8,2048,64)

    int*   idx    = (int*)d_ws;              // NP ints = 2MB
    float* stats  = (float*)d_ws + NP;
    float* stats0 = stats;                   // 64 floats (sum32+sq32)
    float* stats1 = stats + 64;              // 64 floats
    float* stats2 = stats + 128;             // 128 floats (sum64+sq64)

    hipMemsetAsync(stats, 0, 256 * sizeof(float), stream);

    fps_kernel<<<BB, TT, 0, stream>>>(xyz, out_newxyz);
    ballq_kernel<<<BB * SS / 4, 256, 0, stream>>>(xyz, out_newxyz, idx);
    l0_stats_kernel<<<NP / 256, 256, 0, stream>>>(xyz, points, out_newxyz, idx, w0, b0_, stats0);
    l1_stats_kernel<<<NP / 256, 256, 0, stream>>>(xyz, points, out_newxyz, idx,
                                                  w0, b0_, g0, be0, w1, b1_, stats0, stats1);
    l2_stats_kernel<<<NP / 256, 256, 0, stream>>>(xyz, points, out_newxyz, idx,
                                                  w0, b0_, g0, be0, w1, b1_, g1, be1,
                                                  w2, b2_, stats0, stats1, stats2);
    final_kernel<<<NP / 256, 256, 0, stream>>>(xyz, points, out_newxyz, idx,
                                               w0, b0_, g0, be0, w1, b1_, g1, be1,
                                               w2, b2_, g2, be2, stats0, stats1, stats2,
                                               out_points);
}

// Round 9
// 1942.500 us; speedup vs baseline: 1.1416x; 1.0183x over previous
//
#include <hip/hip_runtime.h>
#include <math.h>

#define BB 8
#define NN 8192
#define SS 2048
#define KK 32
#define NP (BB*SS*KK)   /* 524288 points through the MLP */
#define EPSF 1e-5f
#define TT 512          /* fps threads: W=2 waves/SIMD (R4 best config; R5/R6/R7
                           variants all regressed -> R4 inner loop is frozen) */

typedef float v2f __attribute__((ext_vector_type(2)));

// ---------------------------------------------------------------------------
// DPP-based wave64 max of an f64 key (dist_bits<<32 | ~p). Keys are positive
// non-NaN doubles (dist >= 0), so f64 ordering == u64 ordering, and
// v_max_f64 (1 inst) replaces cmp_u64 + 2 cndmask.
// ---------------------------------------------------------------------------
template <int CTRL>
__device__ __forceinline__ double dpp_max_d(double key) {
    int lo = __double2loint(key), hi = __double2hiint(key);
    int nlo = __builtin_amdgcn_update_dpp(lo, lo, CTRL, 0xf, 0xf, false);
    int nhi = __builtin_amdgcn_update_dpp(hi, hi, CTRL, 0xf, 0xf, false);
    return fmax(__hiloint2double(nhi, nlo), key);
}

__device__ __forceinline__ double wave_max_key(double key) {
    key = dpp_max_d<0x111>(key);  // row_shr:1
    key = dpp_max_d<0x112>(key);  // row_shr:2
    key = dpp_max_d<0x114>(key);  // row_shr:4
    key = dpp_max_d<0x118>(key);  // row_shr:8
    key = dpp_max_d<0x142>(key);  // row_bcast:15
    key = dpp_max_d<0x143>(key);  // row_bcast:31
    return key;                   // valid in lane 63
}

// ---------------------------------------------------------------------------
// FPS: one block per batch (cross-WG exchange ~2.5us/iter -> 1 CU/batch is
// structural). R9 = R8/R4 fps VERBATIM (frozen floor) + block-0 zeroing of
// the 256-float stats region (replaces the hipMemsetAsync dispatch; stream
// order makes the zeros visible to all downstream kernels).
// Bit-exact: contract(off), ((dx*dx+dy*dy)+dz*dz), exact coord copies,
// f64 key order == u64 order for positive finite keys; max of (dist,~p)
// == max dist with smallest-global-index tie-break == np.argmax.
// ---------------------------------------------------------------------------
__global__ __launch_bounds__(TT) void fps_kernel(const float* __restrict__ xyz,
                                                 float* __restrict__ out_newxyz,
                                                 float* __restrict__ stats_zero) {
#pragma clang fp contract(off)
    const int PPT = NN / TT;         // 16 points per thread
    const int NPAIR = PPT / 2;       // 8 packed pairs
    const int NW = TT / 64;          // 8 waves
    int b = blockIdx.x;
    int t = threadIdx.x;
    int wid  = t >> 6;               // 0..7
    int lane = t & 63;
    const float* x = xyz + b * NN * 3;
    float* nout = out_newxyz + b * SS * 3;

    if (b == 0 && t < 256) stats_zero[t] = 0.f;    // replaces memset dispatch

    __shared__ float4 lxyz[NN];                    // 128 KB coord copy
    __shared__ __align__(16) double skey[2][NW];   // parity wave keys (f64)

    v2f px2[NPAIR], py2[NPAIR], pz2[NPAIR], d2[NPAIR];
    int lo_c[PPT];                                 // per-slot tie-break ~p (loop-invariant)
#pragma unroll
    for (int s = 0; s < PPT; s++) lo_c[s] = (int)~(unsigned)(t + s * TT);
#pragma unroll
    for (int j = 0; j < NPAIR; j++) {
        int p0 = t + (2 * j) * TT;                    // slot 2j
        int p1 = p0 + TT;                             // slot 2j+1
        float ax = x[p0 * 3 + 0], ay = x[p0 * 3 + 1], az = x[p0 * 3 + 2];
        float bx = x[p1 * 3 + 0], by = x[p1 * 3 + 1], bz = x[p1 * 3 + 2];
        px2[j].x = ax; px2[j].y = bx;
        py2[j].x = ay; py2[j].y = by;
        pz2[j].x = az; pz2[j].y = bz;
        lxyz[p0] = make_float4(ax, ay, az, 0.f);
        lxyz[p1] = make_float4(bx, by, bz, 0.f);
        d2[j].x = 1e10f; d2[j].y = 1e10f;
    }
    __syncthreads();
    float4 c0 = lxyz[0];                              // far = 0 initially
    float cx = c0.x, cy = c0.y, cz = c0.z;

#pragma unroll 2
    for (int it = 0; it < SS; it++) {
        // store from copies so the store's data regs never alias the tail's
        // ds_read destinations (no hidden vmcnt drain on wave 0)
        float sx = cx, sy = cy, sz = cz;
        if (t == 0) {                                  // record current far point
            nout[it * 3 + 0] = sx;
            nout[it * 3 + 1] = sy;
            nout[it * 3 + 2] = sz;
        }
        v2f cxx, cyy, czz;
        cxx.x = cx; cxx.y = cx;
        cyy.x = cy; cyy.y = cy;
        czz.x = cz; czz.y = cz;
        // min-update + in-loop f64 slot keys; 4 independent max_f64 chains
        double acc[4] = {0.0, 0.0, 0.0, 0.0};
#pragma unroll
        for (int j = 0; j < NPAIR; j++) {
            v2f dx = px2[j] - cxx;
            v2f dy = py2[j] - cyy;
            v2f dz = pz2[j] - czz;
            v2f ss = (dx * dx + dy * dy) + dz * dz;
            v2f e  = __builtin_elementwise_min(d2[j], ss);
            d2[j] = e;
            double k0 = __hiloint2double(__float_as_int(e.x), lo_c[2 * j]);
            double k1 = __hiloint2double(__float_as_int(e.y), lo_c[2 * j + 1]);
            double kp = fmax(k0, k1);                  // independent pair-max
            acc[j & 3] = fmax(acc[j & 3], kp);         // static index (unrolled)
        }
        double key = fmax(fmax(acc[0], acc[1]), fmax(acc[2], acc[3]));
        key = wave_max_key(key);                       // DPP, valid in lane 63
        if (lane == 63) skey[it & 1][wid] = key;
        __syncthreads();
        const double2* sk = (const double2*)&skey[it & 1][0];
        double2 k01 = sk[0];                           // 4x ds_read_b128
        double2 k23 = sk[1];
        double2 k45 = sk[2];
        double2 k67 = sk[3];
        double ka = fmax(fmax(k01.x, k01.y), fmax(k23.x, k23.y));
        double kb = fmax(fmax(k45.x, k45.y), fmax(k67.x, k67.y));
        double k  = fmax(ka, kb);                      // depth-3 tree
        int gi = (int)(~(unsigned)__double2loint(k)) & (NN - 1);
        float4 c = lxyz[gi];                           // one broadcast ds_read_b128
        cx = c.x; cy = c.y; cz = c.z;
    }
}

// ---------------------------------------------------------------------------
// Ball query: one wave per query. R9: 4 points per lane per chunk (256 pts).
// 3x float4 loads (16B-aligned: 12*(base+4*lane) % 16 == 0), 32 chunk-iters.
// Ordered compaction preserved: global index = base + 4*lane + slot;
// pre = sum popc(m_i & below) + same-lane lower-slot in-flags;
// first = base + min over slots of 4*(ffs(m_i)-1)+i. Same __f*_rn
// arithmetic, same R2, same truncate/pad semantics as the passing R8 kernel.
// ---------------------------------------------------------------------------
__global__ __launch_bounds__(256) void ballq_kernel(const float* __restrict__ xyz,
                                                    const float* __restrict__ new_xyz,
                                                    int* __restrict__ idx_out) {
    int q    = blockIdx.x * 4 + (threadIdx.x >> 6);
    int lane = threadIdx.x & 63;
    int b    = q >> 11;                        // q / SS
    const float* x = xyz + b * NN * 3;
    const float* c = new_xyz + q * 3;
    float cx = c[0], cy = c[1], cz = c[2];
    int* out = idx_out + q * KK;
    const float R2 = (float)(0.2 * 0.2);       // match reference double->f32 cast

    int count = 0;
    int first = -1;
    unsigned long long below = (1ull << lane) - 1ull;
    for (int base = 0; base < NN; base += 256) {
        int p0 = base + 4 * lane;
        const float4* xp = (const float4*)(x + p0 * 3);
        float4 A  = xp[0];                         // x0 y0 z0 x1
        float4 Bv = xp[1];                         // y1 z1 x2 y2
        float4 Cv = xp[2];                         // z2 x3 y3 z3
        float dx0 = __fsub_rn(A.x,  cx), dy0 = __fsub_rn(A.y,  cy), dz0 = __fsub_rn(A.z,  cz);
        float dx1 = __fsub_rn(A.w,  cx), dy1 = __fsub_rn(Bv.x, cy), dz1 = __fsub_rn(Bv.y, cz);
        float dx2 = __fsub_rn(Bv.z, cx), dy2 = __fsub_rn(Bv.w, cy), dz2 = __fsub_rn(Cv.x, cz);
        float dx3 = __fsub_rn(Cv.y, cx), dy3 = __fsub_rn(Cv.z, cy), dz3 = __fsub_rn(Cv.w, cz);
        float d0 = __fadd_rn(__fadd_rn(__fmul_rn(dx0, dx0), __fmul_rn(dy0, dy0)), __fmul_rn(dz0, dz0));
        float d1 = __fadd_rn(__fadd_rn(__fmul_rn(dx1, dx1), __fmul_rn(dy1, dy1)), __fmul_rn(dz1, dz1));
        float d2 = __fadd_rn(__fadd_rn(__fmul_rn(dx2, dx2), __fmul_rn(dy2, dy2)), __fmul_rn(dz2, dz2));
        float d3 = __fadd_rn(__fadd_rn(__fmul_rn(dx3, dx3), __fmul_rn(dy3, dy3)), __fmul_rn(dz3, dz3));
        bool in0 = !(d0 > R2), in1 = !(d1 > R2), in2 = !(d2 > R2), in3 = !(d3 > R2);
        unsigned long long m0 = __ballot(in0);
        unsigned long long m1 = __ballot(in1);
        unsigned long long m2 = __ballot(in2);
        unsigned long long m3 = __ballot(in3);
        if (first < 0 && (m0 | m1 | m2 | m3) != 0ull) {
            int c0 = m0 ? (4 * (__ffsll(m0) - 1))     : 99999;
            int c1 = m1 ? (4 * (__ffsll(m1) - 1) + 1) : 99999;
            int c2 = m2 ? (4 * (__ffsll(m2) - 1) + 2) : 99999;
            int c3 = m3 ? (4 * (__ffsll(m3) - 1) + 3) : 99999;
            int cma = c0 < c1 ? c0 : c1;
            int cmb = c2 < c3 ? c2 : c3;
            first = base + (cma < cmb ? cma : cmb);
        }
        int pre0 = __popcll(m0 & below) + __popcll(m1 & below)
                 + __popcll(m2 & below) + __popcll(m3 & below);
        int pre1 = pre0 + (in0 ? 1 : 0);
        int pre2 = pre1 + (in1 ? 1 : 0);
        int pre3 = pre2 + (in2 ? 1 : 0);
        int pos0 = count + pre0;
        int pos1 = count + pre1;
        int pos2 = count + pre2;
        int pos3 = count + pre3;
        if (in0 && pos0 < KK) out[pos0] = p0;
        if (in1 && pos1 < KK) out[pos1] = p0 + 1;
        if (in2 && pos2 < KK) out[pos2] = p0 + 2;
        if (in3 && pos3 < KK) out[pos3] = p0 + 3;
        count += __popcll(m0) + __popcll(m1) + __popcll(m2) + __popcll(m3);
        if (count >= KK) break;                 // wave-uniform
    }
    for (int i2 = count + lane; i2 < KK; i2 += 64) out[i2] = first;
}

// ---------------------------------------------------------------------------
// MLP helpers (thread-per-point recompute chain; weights via uniform s_loads)
// ---------------------------------------------------------------------------
__device__ __forceinline__ void load_in6(const float* __restrict__ xyz,
                                         const float* __restrict__ points,
                                         const float* __restrict__ new_xyz,
                                         const int* __restrict__ idx, int p, float inx[6]) {
    int bs = p >> 5;
    int b  = bs >> 11;
    int pt = idx[p];
    const float* xb = xyz + ((long)b * NN + pt) * 3;
    const float* pb = points + ((long)b * NN + pt) * 3;
    const float* nx = new_xyz + bs * 3;
    inx[0] = xb[0] - nx[0];
    inx[1] = xb[1] - nx[1];
    inx[2] = xb[2] - nx[2];
    inx[3] = pb[0];
    inx[4] = pb[1];
    inx[5] = pb[2];
}

template <int CIN, int COUT>
__device__ __forceinline__ void linear(const float* __restrict__ w,
                                       const float* __restrict__ bias,
                                       const float* xin, float* yout) {
#pragma unroll
    for (int o = 0; o < COUT; o++) {
        float acc = bias[o];
#pragma unroll
        for (int j = 0; j < CIN; j++) acc = fmaf(w[o * CIN + j], xin[j], acc);
        yout[o] = acc;
    }
}

// compute per-channel BN scale/shift from raw sums (threads 0..C-1)
template <int C>
__device__ __forceinline__ void bn_coef(const float* __restrict__ stats,
                                        const float* __restrict__ g,
                                        const float* __restrict__ be,
                                        float* s_sc, float* s_sh) {
    int t = threadIdx.x;
    if (t < C) {
        float mean = stats[t] * (1.0f / (float)NP);
        float var  = stats[C + t] * (1.0f / (float)NP) - mean * mean;
        float rstd = 1.0f / sqrtf(var + EPSF);
        float sc = g[t] * rstd;
        s_sc[t] = sc;
        s_sh[t] = be[t] - mean * sc;
    }
    __syncthreads();
}

// R9: BN0 coefficients directly from input moments (layer 0 is LINEAR in the
// 6 gathered inputs): sum_o = w_o.S + N*b_o; sumsq_o = w_o^T M w_o +
// 2 b_o (w_o.S) + N b_o^2, M = sum x x^T (21 upper-tri entries). Same
// mean/var semantics as the old stats0 path, different rounding only.
__device__ __forceinline__ void bn_coef0_mom(const float* __restrict__ mom,
                                             const float* __restrict__ w0,
                                             const float* __restrict__ b0_,
                                             const float* __restrict__ g,
                                             const float* __restrict__ be,
                                             float* s_sc, float* s_sh) {
    int t = threadIdx.x;
    if (t < 32) {
        float w[6];
#pragma unroll
        for (int j = 0; j < 6; j++) w[j] = w0[t * 6 + j];
        float sw = 0.f;
#pragma unroll
        for (int j = 0; j < 6; j++) sw = fmaf(w[j], mom[j], sw);
        float bo = b0_[t];
        float qf = 0.f;
        int mi = 6;
#pragma unroll
        for (int j = 0; j < 6; j++) {
#pragma unroll
            for (int k = j; k < 6; k++) {
                float ww = w[j] * w[k];
                float f  = (j == k) ? 1.f : 2.f;
                qf = fmaf(f * ww, mom[mi], qf);
                mi++;
            }
        }
        float sum   = sw + (float)NP * bo;
        float sumsq = qf + 2.f * bo * sw + (float)NP * bo * bo;
        float mean  = sum * (1.0f / (float)NP);
        float var   = sumsq * (1.0f / (float)NP) - mean * mean;
        float rstd  = 1.0f / sqrtf(var + EPSF);
        float sc = g[t] * rstd;
        s_sc[t] = sc;
        s_sh[t] = be[t] - mean * sc;
    }
    __syncthreads();
}

// block-level channel sums via LDS transpose. R8: parallel 2-level reduce --
// all 256 threads sum 32 rows of one channel (bank = (r+ch)%32, 2 lanes/bank
// = free), 8 partials/channel in ps[], threads<32 fold 8 + one atomic.
template <int C>
__device__ __forceinline__ void accum_stats(const float* y, float* __restrict__ gstats) {
    __shared__ float buf[256][33];
    __shared__ float ps[2][8][33];
    int t = threadIdx.x;
    int ch  = t & 31;
    int seg = t >> 5;                 // 0..7 -> rows seg*32..+32
#pragma unroll
    for (int h = 0; h < C / 32; h++) {
        __syncthreads();
#pragma unroll
        for (int c = 0; c < 32; c++) buf[t][c] = y[h * 32 + c];
        __syncthreads();
        float s = 0.f, sq = 0.f;
#pragma unroll
        for (int r = 0; r < 32; r++) {
            float v = buf[seg * 32 + r][ch];
            s += v;
            sq = fmaf(v, v, sq);
        }
        ps[0][seg][ch] = s;
        ps[1][seg][ch] = sq;
        __syncthreads();
        if (t < 32) {
            float S = 0.f, Q = 0.f;
#pragma unroll
            for (int g = 0; g < 8; g++) {
                S += ps[0][g][t];
                Q += ps[1][g][t];
            }
            atomicAdd(&gstats[h * 32 + t], S);
            atomicAdd(&gstats[C + h * 32 + t], Q);
        }
    }
}

// ---------------------------------------------------------------------------
// R9: layer-0 moments kernel (replaces l0_stats). Per point: 6 sums + 21
// second moments (27 fma vs old 384 fma + accum machinery); block reduce
// via the proven seg/ch parallel pattern; 27 atomics/block.
// ---------------------------------------------------------------------------
__global__ __launch_bounds__(256) void l0_mom_kernel(
    const float* __restrict__ xyz, const float* __restrict__ points,
    const float* __restrict__ new_xyz, const int* __restrict__ idx,
    float* __restrict__ mom) {
    __shared__ float buf[256][33];
    __shared__ float ps[8][33];
    int t = threadIdx.x;
    int p = blockIdx.x * 256 + t;
    float inx[6];
    load_in6(xyz, points, new_xyz, idx, p, inx);
#pragma unroll
    for (int j = 0; j < 6; j++) buf[t][j] = inx[j];
    int mi = 6;
#pragma unroll
    for (int j = 0; j < 6; j++) {
#pragma unroll
        for (int k = j; k < 6; k++) { buf[t][mi] = inx[j] * inx[k]; mi++; }
    }
#pragma unroll
    for (int c = 27; c < 32; c++) buf[t][c] = 0.f;
    __syncthreads();
    int ch = t & 31, seg = t >> 5;
    float s = 0.f;
#pragma unroll
    for (int r = 0; r < 32; r++) s += buf[seg * 32 + r][ch];
    ps[seg][ch] = s;
    __syncthreads();
    if (t < 27) {
        float S = 0.f;
#pragma unroll
        for (int g2 = 0; g2 < 8; g2++) S += ps[g2][t];
        atomicAdd(&mom[t], S);
    }
}

__global__ __launch_bounds__(256) void l1_stats_kernel(
    const float* __restrict__ xyz, const float* __restrict__ points,
    const float* __restrict__ new_xyz, const int* __restrict__ idx,
    const float* __restrict__ w0, const float* __restrict__ b0_,
    const float* __restrict__ g0, const float* __restrict__ be0,
    const float* __restrict__ w1, const float* __restrict__ b1_,
    const float* __restrict__ mom, float* __restrict__ stats1) {
    __shared__ float sc0[32], sh0[32];
    bn_coef0_mom(mom, w0, b0_, g0, be0, sc0, sh0);
    int p = blockIdx.x * 256 + threadIdx.x;
    float inx[6];
    load_in6(xyz, points, new_xyz, idx, p, inx);
    float y0[32];
    linear<6, 32>(w0, b0_, inx, y0);
#pragma unroll
    for (int c = 0; c < 32; c++) y0[c] = fmaxf(fmaf(y0[c], sc0[c], sh0[c]), 0.f);
    float y1[32];
    linear<32, 32>(w1, b1_, y0, y1);
    accum_stats<32>(y1, stats1);
}

__global__ __launch_bounds__(256) void l2_stats_kernel(
    const float* __restrict__ xyz, const float* __restrict__ points,
    const float* __restrict__ new_xyz, const int* __restrict__ idx,
    const float* __restrict__ w0, const float* __restrict__ b0_,
    const float* __restrict__ g0, const float* __restrict__ be0,
    const float* __restrict__ w1, const float* __restrict__ b1_,
    const float* __restrict__ g1, const float* __restrict__ be1,
    const float* __restrict__ w2, const float* __restrict__ b2_,
    const float* __restrict__ mom, const float* __restrict__ stats1,
    float* __restrict__ stats2) {
    __shared__ float sc0[32], sh0[32], sc1[32], sh1[32];
    bn_coef0_mom(mom, w0, b0_, g0, be0, sc0, sh0);
    bn_coef<32>(stats1, g1, be1, sc1, sh1);
    int p = blockIdx.x * 256 + threadIdx.x;
    float inx[6];
    load_in6(xyz, points, new_xyz, idx, p, inx);
    float y0[32];
    linear<6, 32>(w0, b0_, inx, y0);
#pragma unroll
    for (int c = 0; c < 32; c++) y0[c] = fmaxf(fmaf(y0[c], sc0[c], sh0[c]), 0.f);
    float y1[32];
    linear<32, 32>(w1, b1_, y0, y1);
#pragma unroll
    for (int c = 0; c < 32; c++) y1[c] = fmaxf(fmaf(y1[c], sc1[c], sh1[c]), 0.f);
    float y2[64];
    linear<32, 64>(w2, b2_, y1, y2);
    accum_stats<64>(y2, stats2);
}

__global__ __launch_bounds__(256) void final_kernel(
    const float* __restrict__ xyz, const float* __restrict__ points,
    const float* __restrict__ new_xyz, const int* __restrict__ idx,
    const float* __restrict__ w0, const float* __restrict__ b0_,
    const float* __restrict__ g0, const float* __restrict__ be0,
    const float* __restrict__ w1, const float* __restrict__ b1_,
    const float* __restrict__ g1, const float* __restrict__ be1,
    const float* __restrict__ w2, const float* __restrict__ b2_,
    const float* __restrict__ g2, const float* __restrict__ be2,
    const float* __restrict__ mom, const float* __restrict__ stats1,
    const float* __restrict__ stats2, float* __restrict__ out_points) {
    __shared__ float sc0[32], sh0[32], sc1[32], sh1[32], sc2[64], sh2[64];
    bn_coef0_mom(mom, w0, b0_, g0, be0, sc0, sh0);
    bn_coef<32>(stats1, g1, be1, sc1, sh1);
    bn_coef<64>(stats2, g2, be2, sc2, sh2);
    int p = blockIdx.x * 256 + threadIdx.x;
    float inx[6];
    load_in6(xyz, points, new_xyz, idx, p, inx);
    float y0[32];
    linear<6, 32>(w0, b0_, inx, y0);
#pragma unroll
    for (int c = 0; c < 32; c++) y0[c] = fmaxf(fmaf(y0[c], sc0[c], sh0[c]), 0.f);
    float y1[32];
    linear<32, 32>(w1, b1_, y0, y1);
#pragma unroll
    for (int c = 0; c < 32; c++) y1[c] = fmaxf(fmaf(y1[c], sc1[c], sh1[c]), 0.f);
    float y2[64];
    linear<32, 64>(w2, b2_, y1, y2);
    // BN + relu + max over k (k == lane&31; butterfly within each 32-lane half)
#pragma unroll
    for (int c = 0; c < 64; c++) {
        float v = fmaxf(fmaf(y2[c], sc2[c], sh2[c]), 0.f);
#pragma unroll
        for (int off = 1; off < 32; off <<= 1)
            v = fmaxf(v, __shfl_xor(v, off));
        y2[c] = v;
    }
    int lane = threadIdx.x & 63;
    if ((lane & 31) == 0) {                     // k == 0 lanes write their (b,s) row
        int bs = p >> 5;
        float4* o = (float4*)(out_points + (long)bs * 64);
#pragma unroll
        for (int c4 = 0; c4 < 16; c4++)
            o[c4] = make_float4(y2[c4 * 4], y2[c4 * 4 + 1], y2[c4 * 4 + 2], y2[c4 * 4 + 3]);
    }
}

// ---------------------------------------------------------------------------
extern "C" void kernel_launch(void* const* d_in, const int* in_sizes, int n_in,
                              void* d_out, int out_size, void* d_ws, size_t ws_size,
                              hipStream_t stream) {
    (void)in_sizes; (void)n_in; (void)out_size; (void)ws_size;
    const float* xyz    = (const float*)d_in[0];
    const float* points = (const float*)d_in[1];
    const float* w0  = (const float*)d_in[2];
    const float* b0_ = (const float*)d_in[3];
    const float* g0  = (const float*)d_in[4];
    const float* be0 = (const float*)d_in[5];
    const float* w1  = (const float*)d_in[6];
    const float* b1_ = (const float*)d_in[7];
    const float* g1  = (const float*)d_in[8];
    const float* be1 = (const float*)d_in[9];
    const float* w2  = (const float*)d_in[10];
    const float* b2_ = (const float*)d_in[11];
    const float* g2  = (const float*)d_in[12];
    const float* be2 = (const float*)d_in[13];

    float* out        = (float*)d_out;
    float* out_newxyz = out;                 // (8,2048,3)
    float* out_points = out + BB * SS * 3;   // (8,2048,64)

    int*   idx    = (int*)d_ws;              // NP ints = 2MB
    float* stats  = (float*)d_ws + NP;
    float* mom    = stats;                   // 27 floats (6 sums + 21 moments)
    float* stats1 = stats + 64;              // 64 floats
    float* stats2 = stats + 128;             // 128 floats (sum64+sq64)

    fps_kernel<<<BB, TT, 0, stream>>>(xyz, out_newxyz, stats);
    ballq_kernel<<<BB * SS / 4, 256, 0, stream>>>(xyz, out_newxyz, idx);
    l0_mom_kernel<<<NP / 256, 256, 0, stream>>>(xyz, points, out_newxyz, idx, mom);
    l1_stats_kernel<<<NP / 256, 256, 0, stream>>>(xyz, points, out_newxyz, idx,
                                                  w0, b0_, g0, be0, w1, b1_, mom, stats1);
    l2_stats_kernel<<<NP / 256, 256, 0, stream>>>(xyz, points, out_newxyz, idx,
                                                  w0, b0_, g0, be0, w1, b1_, g1, be1,
                                                  w2, b2_, mom, stats1, stats2);
    final_kernel<<<NP / 256, 256, 0, stream>>>(xyz, points, out_newxyz, idx,
                                               w0, b0_, g0, be0, w1, b1_, g1, be1,
                                               w2, b2_, g2, be2, mom, stats1, stats2,
                                               out_points);
}